// Round 6
// baseline (156.231 us; speedup 1.0000x reference)
//
#include <hip/hip_runtime.h>
#include <hip/hip_bf16.h>

#define BB 4
#define SS 2
#define DD 16
#define CH 32          // S*D
#define PP (512*512)   // pixels per item
#define NSEGC 64
#define MARGINF 0.25f

// ---- k_sums geometry ----
#define CHUNK 1024              // pixels per block
#define NCHUNK (PP/CHUNK)       // 256 chunks per batch -> grid 1024

// ---- k_pull geometry ----
#define PXB2 512                // pixels per block
#define NCHK2 (PP/PXB2)         // 512 chunks per batch -> grid 2048
#define CSTR 36                 // centL row stride (16B-aligned rows, bank-spread)

typedef __attribute__((ext_vector_type(4))) float  f32x4;
typedef __attribute__((ext_vector_type(8))) short  short8;

__device__ inline short f2bf(float x) {
    union { __hip_bfloat16 h; short s; } u;
    u.h = __float2bfloat16(x);   // RNE
    return u.s;
}

// ---------------- kernel A: segment sums + counts via one-hot MFMA ----------------
__global__ __launch_bounds__(256) void k_sums(const float* __restrict__ preds,
                                              const int* __restrict__ labels,
                                              float* __restrict__ g_sums,    // [B][CH][NSEG]
                                              float* __restrict__ g_counts)  // [B][NSEG]
{
    __shared__ int   labs[CHUNK];
    __shared__ float buf[4][CH][68];     // per-wave result, [ch][seg(64)+pad]
    __shared__ float cbuf[4][NSEGC];

    const int b    = blockIdx.x / NCHUNK;
    const int base = (blockIdx.x % NCHUNK) * CHUNK;
    const int tid  = threadIdx.x;
    const int w    = tid >> 6;           // wave 0..3
    const int l    = tid & 63;
    const int lm   = l & 15;             // A-row / B-col / D-col
    const int lk   = l >> 4;             // k-group

    ((int4*)labs)[tid] = ((const int4*)(labels + (size_t)b * PP + base))[tid];

    f32x4 acc[4][2];
    f32x4 accc[4];
#pragma unroll
    for (int mt = 0; mt < 4; ++mt) {
        accc[mt] = f32x4{0.f, 0.f, 0.f, 0.f};
#pragma unroll
        for (int nt = 0; nt < 2; ++nt) acc[mt][nt] = f32x4{0.f, 0.f, 0.f, 0.f};
    }
    short8 ones;
#pragma unroll
    for (int j = 0; j < 8; ++j) ones[j] = (short)0x3F80;  // bf16 1.0

    __syncthreads();

    const float* pb = preds + (size_t)b * CH * PP + base;

#pragma unroll 2
    for (int c = 0; c < 8; ++c) {
        const int kbase = (w * 8 + c) * 32 + lk * 8;
        const int4 L0 = *(const int4*)&labs[kbase];
        const int4 L1 = *(const int4*)&labs[kbase + 4];
        const int labv[8] = {L0.x, L0.y, L0.z, L0.w, L1.x, L1.y, L1.z, L1.w};

        short8 af[4];
#pragma unroll
        for (int mt = 0; mt < 4; ++mt) {
            const int target = mt * 16 + lm;
#pragma unroll
            for (int j = 0; j < 8; ++j)
                af[mt][j] = (labv[j] == target) ? (short)0x3F80 : (short)0;
        }

#pragma unroll
        for (int nt = 0; nt < 2; ++nt) {
            const float* src = pb + (size_t)(nt * 16 + lm) * PP + kbase;
            const float4 v0 = ((const float4*)src)[0];
            const float4 v1 = ((const float4*)src)[1];
            short8 bf;
            bf[0] = f2bf(v0.x); bf[1] = f2bf(v0.y); bf[2] = f2bf(v0.z); bf[3] = f2bf(v0.w);
            bf[4] = f2bf(v1.x); bf[5] = f2bf(v1.y); bf[6] = f2bf(v1.z); bf[7] = f2bf(v1.w);
#pragma unroll
            for (int mt = 0; mt < 4; ++mt)
                acc[mt][nt] = __builtin_amdgcn_mfma_f32_16x16x32_bf16(af[mt], bf, acc[mt][nt], 0, 0, 0);
        }
#pragma unroll
        for (int mt = 0; mt < 4; ++mt)
            accc[mt] = __builtin_amdgcn_mfma_f32_16x16x32_bf16(af[mt], ones, accc[mt], 0, 0, 0);
    }

    // D layout: col = lane&15, row = (lane>>4)*4 + reg  (m89-verified)
#pragma unroll
    for (int mt = 0; mt < 4; ++mt) {
#pragma unroll
        for (int nt = 0; nt < 2; ++nt)
            *(f32x4*)&buf[w][nt * 16 + lm][mt * 16 + lk * 4] = acc[mt][nt];
        if (lm == 0)
            *(f32x4*)&cbuf[w][mt * 16 + lk * 4] = accc[mt];
    }
    __syncthreads();

    for (int i = tid; i < CH * NSEGC; i += 256) {
        const int col = i >> 6, row = i & 63;   // i = ch*64 + seg
        const float s = buf[0][col][row] + buf[1][col][row] + buf[2][col][row] + buf[3][col][row];
        atomicAdd(&g_sums[(size_t)b * CH * NSEGC + i], s);
    }
    if (tid < NSEGC)
        atomicAdd(&g_counts[b * NSEGC + tid],
                  cbuf[0][tid] + cbuf[1][tid] + cbuf[2][tid] + cbuf[3][tid]);
}

// ---------------- kernel B: centroids + push loss (one block per batch) ----------------
__global__ __launch_bounds__(256) void k_push(const float* __restrict__ g_sums,
                                              const float* __restrict__ g_counts,
                                              float* __restrict__ g_cent,   // [B][NSEG][CH]
                                              float* __restrict__ g_push)   // [B]
{
    __shared__ float centB[CH * NSEGC];  // [ch][seg]
    __shared__ float red[4];
    const int b = blockIdx.x;
    const int tid = threadIdx.x;

    for (int i = tid; i < CH * NSEGC; i += 256) {
        const int ch = i >> 6, seg = i & 63;
        const float cnt = fmaxf(g_counts[b * NSEGC + seg], 1.0f);
        const float c = g_sums[(size_t)b * CH * NSEGC + i] / cnt;
        centB[i] = c;
        g_cent[(size_t)b * NSEGC * CH + seg * CH + ch] = c;
    }
    __syncthreads();

    float acc = 0.f;
    for (int t = tid; t < SS * 2016; t += 256) {
        const int s = t / 2016;
        int rem = t % 2016;
        int i = 0;
        while (rem >= 63 - i) { rem -= 63 - i; ++i; }
        const int j = i + 1 + rem;
        float dsum = 0.f;
#pragma unroll
        for (int d = 0; d < DD; ++d) {
            const int ch = s * DD + d;
            dsum += fabsf(centB[ch * NSEGC + i] - centB[ch * NSEGC + j]);
        }
        const float cd = dsum * (1.f / DD);
        const float r = fmaxf(MARGINF - cd, 0.f);
        acc += r * r;
    }
    for (int o = 32; o > 0; o >>= 1) acc += __shfl_down(acc, o, 64);
    if ((tid & 63) == 0) red[tid >> 6] = acc;
    __syncthreads();
    if (tid == 0)
        g_push[b] = (red[0] + red[1] + red[2] + red[3]) * (1.0f / (SS * 2016));
}

// ---------------- kernel C: pull loss + last-block finalize ----------------
__global__ __launch_bounds__(256, 6) void k_pull(const float* __restrict__ preds,
                                                 const int* __restrict__ labels,
                                                 const float* __restrict__ g_cent, // [B][NSEG][CH]
                                                 float* __restrict__ g_pull,       // [B]
                                                 const float* __restrict__ g_push, // [B]
                                                 unsigned* __restrict__ g_done,
                                                 float* __restrict__ out)
{
    __shared__ float centL[NSEGC * CSTR];   // [seg][ch]
    __shared__ float red[4];
    const int b    = blockIdx.x >> 9;               // / NCHK2
    const int base = (blockIdx.x & (NCHK2 - 1)) * PXB2;
    const int tid  = threadIdx.x;

    for (int i = tid; i < NSEGC * CH; i += 256) {
        const int seg = i >> 5, ch = i & 31;
        centL[seg * CSTR + ch] = g_cent[(size_t)b * NSEGC * CH + i];  // coalesced
    }
    const int2 lv = ((const int2*)(labels + (size_t)b * PP + base))[tid];
    const int c0 = lv.x * CSTR, c1 = lv.y * CSTR;
    __syncthreads();

    const float* pb = preds + (size_t)b * CH * PP + base;
    float total = 0.f;
#pragma unroll
    for (int s = 0; s < SS; ++s) {
        float a0 = 0.f, a1 = 0.f;
#pragma unroll
        for (int d = 0; d < DD; ++d) {           // fully unrolled: 16 independent loads in flight
            const int ch = s * DD + d;
            const float2 v = ((const float2*)(pb + (size_t)ch * PP))[tid];
            a0 += fabsf(v.x - centL[c0 + ch]);
            a1 += fabsf(v.y - centL[c1 + ch]);
        }
        float q;
        q = a0 * (1.f / DD); total += q * q;
        q = a1 * (1.f / DD); total += q * q;
    }
    for (int o = 32; o > 0; o >>= 1) total += __shfl_down(total, o, 64);
    if ((tid & 63) == 0) red[tid >> 6] = total;
    __syncthreads();

    if (tid == 0) {
        atomicAdd(&g_pull[b], red[0] + red[1] + red[2] + red[3]);
        __threadfence();                               // order my atomics before the counter
        const unsigned prev = atomicAdd(g_done, 1u);
        if (prev == gridDim.x - 1) {                   // last block: all g_pull visible
            float accf = 0.f;
            for (int bb = 0; bb < BB; ++bb) {
                const float pu = atomicAdd(&g_pull[bb], 0.0f);   // coherent read
                const float ph = g_push[bb];                     // written by prior kernel
                accf += ph + 0.1f * (pu * (1.0f / (SS * PP)));
            }
            out[0] = accf * (1.0f / BB);
        }
    }
}

extern "C" void kernel_launch(void* const* d_in, const int* in_sizes, int n_in,
                              void* d_out, int out_size, void* d_ws, size_t ws_size,
                              hipStream_t stream) {
    const float* preds  = (const float*)d_in[0];
    const int*   labels = (const int*)d_in[1];

    float* ws       = (float*)d_ws;
    float* g_sums   = ws;                              // B*CH*NSEG = 8192
    float* g_counts = g_sums + BB * CH * NSEGC;        // B*NSEG    = 256
    float* g_pull   = g_counts + BB * NSEGC;           // B         = 4
    float* g_push   = g_pull + BB;                     // B         = 4
    unsigned* g_done = (unsigned*)(g_push + BB);       // 1
    float* g_cent   = (float*)(g_done + 1);            // B*NSEG*CH = 8192 (g_done+pad handled by +1)

    // zero accumulated region (sums, counts, pull, push, done) — replays must not accumulate
    hipMemsetAsync(d_ws, 0,
                   (size_t)(BB * CH * NSEGC + BB * NSEGC + BB + BB + 1) * sizeof(float),
                   stream);

    k_sums<<<BB * NCHUNK, 256, 0, stream>>>(preds, labels, g_sums, g_counts);
    k_push<<<BB, 256, 0, stream>>>(g_sums, g_counts, g_cent, g_push);
    k_pull<<<BB * NCHK2, 256, 0, stream>>>(preds, labels, g_cent, g_pull, g_push,
                                           g_done, (float*)d_out);
}

// Round 7
// 118.324 us; speedup vs baseline: 1.3204x; 1.3204x over previous
//
#include <hip/hip_runtime.h>
#include <hip/hip_bf16.h>

#define BB 4
#define SS 2
#define DD 16
#define CH 32          // S*D
#define PP (512*512)   // pixels per item
#define NSEGC 64
#define MARGINF 0.25f

// ---- shared geometry: 1024 px per block, 256 blocks per batch -> grid 1024 ----
#define CHUNK 1024
#define NCHUNK (PP/CHUNK)
#define CSTR 33                 // centL row stride: bank=(label+ch)%32 -> free 2-way

typedef __attribute__((ext_vector_type(4))) float  f32x4;
typedef __attribute__((ext_vector_type(8))) short  short8;

__device__ inline short f2bf(float x) {
    union { __hip_bfloat16 h; short s; } u;
    u.h = __float2bfloat16(x);   // RNE
    return u.s;
}

// ---------------- kernel A: segment sums + counts via one-hot MFMA ----------------
__global__ __launch_bounds__(256) void k_sums(const float* __restrict__ preds,
                                              const int* __restrict__ labels,
                                              float* __restrict__ g_sums,    // [B][CH][NSEG]
                                              float* __restrict__ g_counts)  // [B][NSEG]
{
    __shared__ int   labs[CHUNK];
    __shared__ float buf[4][CH][68];     // per-wave result, [ch][seg(64)+pad]
    __shared__ float cbuf[4][NSEGC];

    const int b    = blockIdx.x / NCHUNK;
    const int base = (blockIdx.x % NCHUNK) * CHUNK;
    const int tid  = threadIdx.x;
    const int w    = tid >> 6;           // wave 0..3
    const int l    = tid & 63;
    const int lm   = l & 15;             // A-row / B-col / D-col
    const int lk   = l >> 4;             // k-group

    ((int4*)labs)[tid] = ((const int4*)(labels + (size_t)b * PP + base))[tid];

    f32x4 acc[4][2];
    f32x4 accc[4];
#pragma unroll
    for (int mt = 0; mt < 4; ++mt) {
        accc[mt] = f32x4{0.f, 0.f, 0.f, 0.f};
#pragma unroll
        for (int nt = 0; nt < 2; ++nt) acc[mt][nt] = f32x4{0.f, 0.f, 0.f, 0.f};
    }
    short8 ones;
#pragma unroll
    for (int j = 0; j < 8; ++j) ones[j] = (short)0x3F80;  // bf16 1.0

    __syncthreads();

    const float* pb = preds + (size_t)b * CH * PP + base;

#pragma unroll 2
    for (int c = 0; c < 8; ++c) {
        const int kbase = (w * 8 + c) * 32 + lk * 8;
        const int4 L0 = *(const int4*)&labs[kbase];
        const int4 L1 = *(const int4*)&labs[kbase + 4];
        const int labv[8] = {L0.x, L0.y, L0.z, L0.w, L1.x, L1.y, L1.z, L1.w};

        short8 af[4];
#pragma unroll
        for (int mt = 0; mt < 4; ++mt) {
            const int target = mt * 16 + lm;
#pragma unroll
            for (int j = 0; j < 8; ++j)
                af[mt][j] = (labv[j] == target) ? (short)0x3F80 : (short)0;
        }

#pragma unroll
        for (int nt = 0; nt < 2; ++nt) {
            const float* src = pb + (size_t)(nt * 16 + lm) * PP + kbase;
            const float4 v0 = ((const float4*)src)[0];
            const float4 v1 = ((const float4*)src)[1];
            short8 bf;
            bf[0] = f2bf(v0.x); bf[1] = f2bf(v0.y); bf[2] = f2bf(v0.z); bf[3] = f2bf(v0.w);
            bf[4] = f2bf(v1.x); bf[5] = f2bf(v1.y); bf[6] = f2bf(v1.z); bf[7] = f2bf(v1.w);
#pragma unroll
            for (int mt = 0; mt < 4; ++mt)
                acc[mt][nt] = __builtin_amdgcn_mfma_f32_16x16x32_bf16(af[mt], bf, acc[mt][nt], 0, 0, 0);
        }
#pragma unroll
        for (int mt = 0; mt < 4; ++mt)
            accc[mt] = __builtin_amdgcn_mfma_f32_16x16x32_bf16(af[mt], ones, accc[mt], 0, 0, 0);
    }

    // D layout: col = lane&15, row = (lane>>4)*4 + reg  (m89-verified)
#pragma unroll
    for (int mt = 0; mt < 4; ++mt) {
#pragma unroll
        for (int nt = 0; nt < 2; ++nt)
            *(f32x4*)&buf[w][nt * 16 + lm][mt * 16 + lk * 4] = acc[mt][nt];
        if (lm == 0)
            *(f32x4*)&cbuf[w][mt * 16 + lk * 4] = accc[mt];
    }
    __syncthreads();

    for (int i = tid; i < CH * NSEGC; i += 256) {
        const int col = i >> 6, row = i & 63;   // i = ch*64 + seg
        const float s = buf[0][col][row] + buf[1][col][row] + buf[2][col][row] + buf[3][col][row];
        atomicAdd(&g_sums[(size_t)b * CH * NSEGC + i], s);
    }
    if (tid < NSEGC)
        atomicAdd(&g_counts[b * NSEGC + tid],
                  cbuf[0][tid] + cbuf[1][tid] + cbuf[2][tid] + cbuf[3][tid]);
}

// ---------------- kernel B: centroids + push loss (one block per batch) ----------------
__global__ __launch_bounds__(256) void k_push(const float* __restrict__ g_sums,
                                              const float* __restrict__ g_counts,
                                              float* __restrict__ g_cent,   // [B][NSEG][CH]
                                              float* __restrict__ g_push)   // [B]
{
    __shared__ float centB[CH * NSEGC];  // [ch][seg]
    __shared__ float red[4];
    const int b = blockIdx.x;
    const int tid = threadIdx.x;

    for (int i = tid; i < CH * NSEGC; i += 256) {
        const int ch = i >> 6, seg = i & 63;
        const float cnt = fmaxf(g_counts[b * NSEGC + seg], 1.0f);
        const float c = g_sums[(size_t)b * CH * NSEGC + i] / cnt;
        centB[i] = c;
        g_cent[(size_t)b * NSEGC * CH + seg * CH + ch] = c;
    }
    __syncthreads();

    float acc = 0.f;
    for (int t = tid; t < SS * 2016; t += 256) {
        const int s = t / 2016;
        int rem = t % 2016;
        int i = 0;
        while (rem >= 63 - i) { rem -= 63 - i; ++i; }
        const int j = i + 1 + rem;
        float dsum = 0.f;
#pragma unroll
        for (int d = 0; d < DD; ++d) {
            const int ch = s * DD + d;
            dsum += fabsf(centB[ch * NSEGC + i] - centB[ch * NSEGC + j]);
        }
        const float cd = dsum * (1.f / DD);
        const float r = fmaxf(MARGINF - cd, 0.f);
        acc += r * r;
    }
    for (int o = 32; o > 0; o >>= 1) acc += __shfl_down(acc, o, 64);
    if ((tid & 63) == 0) red[tid >> 6] = acc;
    __syncthreads();
    if (tid == 0)
        g_push[b] = (red[0] + red[1] + red[2] + red[3]) * (1.0f / (SS * 2016));
}

// ---------------- kernel C: pull loss + last-block finalize ----------------
__global__ __launch_bounds__(256) void k_pull(const float* __restrict__ preds,
                                              const int* __restrict__ labels,
                                              const float* __restrict__ g_cent, // [B][NSEG][CH]
                                              float* __restrict__ g_pull,       // [B]
                                              const float* __restrict__ g_push, // [B]
                                              unsigned* __restrict__ g_done,
                                              float* __restrict__ out)
{
    __shared__ float centL[NSEGC * CSTR];   // [seg][ch]
    __shared__ float red[4];
    const int b    = blockIdx.x / NCHUNK;
    const int base = (blockIdx.x % NCHUNK) * CHUNK;
    const int tid  = threadIdx.x;

    for (int i = tid; i < NSEGC * CH; i += 256) {
        const int seg = i >> 5, ch = i & 31;
        centL[seg * CSTR + ch] = g_cent[(size_t)b * NSEGC * CH + i];  // coalesced
    }
    const int4 lv = ((const int4*)(labels + (size_t)b * PP + base))[tid];
    const int c0 = lv.x * CSTR, c1 = lv.y * CSTR, c2 = lv.z * CSTR, c3 = lv.w * CSTR;
    __syncthreads();

    const float* pb = preds + (size_t)b * CH * PP + base;
    float total = 0.f;
#pragma unroll
    for (int s = 0; s < SS; ++s) {
        // issue ALL 16 channel loads for this s-half before consuming: 256 B/lane in flight
        float4 v[16];
#pragma unroll
        for (int d = 0; d < DD; ++d)
            v[d] = ((const float4*)(pb + (size_t)(s * DD + d) * PP))[tid];

        float a0 = 0.f, a1 = 0.f, a2 = 0.f, a3 = 0.f;
#pragma unroll
        for (int d = 0; d < DD; ++d) {
            const int ch = s * DD + d;
            a0 += fabsf(v[d].x - centL[c0 + ch]);
            a1 += fabsf(v[d].y - centL[c1 + ch]);
            a2 += fabsf(v[d].z - centL[c2 + ch]);
            a3 += fabsf(v[d].w - centL[c3 + ch]);
        }
        float q;
        q = a0 * (1.f / DD); total += q * q;
        q = a1 * (1.f / DD); total += q * q;
        q = a2 * (1.f / DD); total += q * q;
        q = a3 * (1.f / DD); total += q * q;
    }
    for (int o = 32; o > 0; o >>= 1) total += __shfl_down(total, o, 64);
    if ((tid & 63) == 0) red[tid >> 6] = total;
    __syncthreads();

    if (tid == 0) {
        atomicAdd(&g_pull[b], red[0] + red[1] + red[2] + red[3]);
        __threadfence();                               // order my atomics before the counter
        const unsigned prev = atomicAdd(g_done, 1u);
        if (prev == gridDim.x - 1) {                   // last block: all g_pull visible
            float accf = 0.f;
            for (int bb = 0; bb < BB; ++bb) {
                const float pu = atomicAdd(&g_pull[bb], 0.0f);   // coherent read
                const float ph = g_push[bb];                     // written by prior kernel
                accf += ph + 0.1f * (pu * (1.0f / (SS * PP)));
            }
            out[0] = accf * (1.0f / BB);
        }
    }
}

extern "C" void kernel_launch(void* const* d_in, const int* in_sizes, int n_in,
                              void* d_out, int out_size, void* d_ws, size_t ws_size,
                              hipStream_t stream) {
    const float* preds  = (const float*)d_in[0];
    const int*   labels = (const int*)d_in[1];

    float* ws       = (float*)d_ws;
    float* g_sums   = ws;                              // B*CH*NSEG = 8192
    float* g_counts = g_sums + BB * CH * NSEGC;        // B*NSEG    = 256
    float* g_pull   = g_counts + BB * NSEGC;           // B         = 4
    float* g_push   = g_pull + BB;                     // B         = 4
    unsigned* g_done = (unsigned*)(g_push + BB);       // 1
    float* g_cent   = (float*)(g_done + 1);            // B*NSEG*CH = 8192

    // zero accumulated region (sums, counts, pull, push, done) — replays must not accumulate
    hipMemsetAsync(d_ws, 0,
                   (size_t)(BB * CH * NSEGC + BB * NSEGC + BB + BB + 1) * sizeof(float),
                   stream);

    k_sums<<<BB * NCHUNK, 256, 0, stream>>>(preds, labels, g_sums, g_counts);
    k_push<<<BB, 256, 0, stream>>>(g_sums, g_counts, g_cent, g_push);
    k_pull<<<BB * NCHUNK, 256, 0, stream>>>(preds, labels, g_cent, g_pull, g_push,
                                            g_done, (float*)d_out);
}

// Round 8
// 100.185 us; speedup vs baseline: 1.5594x; 1.1811x over previous
//
#include <hip/hip_runtime.h>
#include <hip/hip_bf16.h>

#define BB 4
#define SS 2
#define DD 16
#define CH 32          // S*D
#define PP (512*512)   // pixels per item
#define NSEGC 64
#define MARGINF 0.25f

// ---- k_sums geometry: 1024 px per block, grid 1024 ----
#define CHUNK 1024
#define NCHUNK (PP/CHUNK)
// ---- k_pull geometry: 2048 px per block (8 px/thread), grid 512 ----
#define PXP 2048
#define NCHKP (PP/PXP)          // 128 per batch
#define CSTR 33                 // centL row stride: bank=(label+ch)%32 -> ~2-way (free)

typedef __attribute__((ext_vector_type(4))) float  f32x4;
typedef __attribute__((ext_vector_type(8))) short  short8;

__device__ inline short f2bf(float x) {
    union { __hip_bfloat16 h; short s; } u;
    u.h = __float2bfloat16(x);   // RNE
    return u.s;
}

// ---------------- kernel A: segment sums + counts via one-hot MFMA ----------------
// Also writes a bf16 shadow copy of preds (t_bf, channel-major) for the pull pass.
__global__ __launch_bounds__(256) void k_sums(const float* __restrict__ preds,
                                              const int* __restrict__ labels,
                                              float* __restrict__ g_sums,    // [B][CH][NSEG]
                                              float* __restrict__ g_counts,  // [B][NSEG]
                                              unsigned short* __restrict__ t_bf) // [B][CH][P]
{
    __shared__ int   labs[CHUNK];
    __shared__ float buf[4][CH][68];     // per-wave result, [ch][seg(64)+pad]
    __shared__ float cbuf[4][NSEGC];

    const int b    = blockIdx.x / NCHUNK;
    const int base = (blockIdx.x % NCHUNK) * CHUNK;
    const int tid  = threadIdx.x;
    const int w    = tid >> 6;           // wave 0..3
    const int l    = tid & 63;
    const int lm   = l & 15;             // A-row / B-col / D-col
    const int lk   = l >> 4;             // k-group

    ((int4*)labs)[tid] = ((const int4*)(labels + (size_t)b * PP + base))[tid];

    f32x4 acc[4][2];
    f32x4 accc[4];
#pragma unroll
    for (int mt = 0; mt < 4; ++mt) {
        accc[mt] = f32x4{0.f, 0.f, 0.f, 0.f};
#pragma unroll
        for (int nt = 0; nt < 2; ++nt) acc[mt][nt] = f32x4{0.f, 0.f, 0.f, 0.f};
    }
    short8 ones;
#pragma unroll
    for (int j = 0; j < 8; ++j) ones[j] = (short)0x3F80;  // bf16 1.0

    __syncthreads();

    const float* pb = preds + (size_t)b * CH * PP + base;
    unsigned short* tbw = t_bf + ((size_t)b * CH + lm) * PP + base;   // channel lm base

#pragma unroll 2
    for (int c = 0; c < 8; ++c) {
        const int kbase = (w * 8 + c) * 32 + lk * 8;
        const int4 L0 = *(const int4*)&labs[kbase];
        const int4 L1 = *(const int4*)&labs[kbase + 4];
        const int labv[8] = {L0.x, L0.y, L0.z, L0.w, L1.x, L1.y, L1.z, L1.w};

        short8 af[4];
#pragma unroll
        for (int mt = 0; mt < 4; ++mt) {
            const int target = mt * 16 + lm;
#pragma unroll
            for (int j = 0; j < 8; ++j)
                af[mt][j] = (labv[j] == target) ? (short)0x3F80 : (short)0;
        }

#pragma unroll
        for (int nt = 0; nt < 2; ++nt) {
            const float* src = pb + (size_t)(nt * 16 + lm) * PP + kbase;
            const float4 v0 = ((const float4*)src)[0];
            const float4 v1 = ((const float4*)src)[1];
            short8 bf;
            bf[0] = f2bf(v0.x); bf[1] = f2bf(v0.y); bf[2] = f2bf(v0.z); bf[3] = f2bf(v0.w);
            bf[4] = f2bf(v1.x); bf[5] = f2bf(v1.y); bf[6] = f2bf(v1.z); bf[7] = f2bf(v1.w);
            // bf16 shadow store (fire-and-forget, consumed by k_pull)
            *(short8*)(tbw + (size_t)(nt * 16) * PP + kbase) = bf;
#pragma unroll
            for (int mt = 0; mt < 4; ++mt)
                acc[mt][nt] = __builtin_amdgcn_mfma_f32_16x16x32_bf16(af[mt], bf, acc[mt][nt], 0, 0, 0);
        }
#pragma unroll
        for (int mt = 0; mt < 4; ++mt)
            accc[mt] = __builtin_amdgcn_mfma_f32_16x16x32_bf16(af[mt], ones, accc[mt], 0, 0, 0);
    }

    // D layout: col = lane&15, row = (lane>>4)*4 + reg  (m89-verified)
#pragma unroll
    for (int mt = 0; mt < 4; ++mt) {
#pragma unroll
        for (int nt = 0; nt < 2; ++nt)
            *(f32x4*)&buf[w][nt * 16 + lm][mt * 16 + lk * 4] = acc[mt][nt];
        if (lm == 0)
            *(f32x4*)&cbuf[w][mt * 16 + lk * 4] = accc[mt];
    }
    __syncthreads();

    for (int i = tid; i < CH * NSEGC; i += 256) {
        const int col = i >> 6, row = i & 63;   // i = ch*64 + seg
        const float s = buf[0][col][row] + buf[1][col][row] + buf[2][col][row] + buf[3][col][row];
        atomicAdd(&g_sums[(size_t)b * CH * NSEGC + i], s);
    }
    if (tid < NSEGC)
        atomicAdd(&g_counts[b * NSEGC + tid],
                  cbuf[0][tid] + cbuf[1][tid] + cbuf[2][tid] + cbuf[3][tid]);
}

// ---------------- kernel B: centroids + push loss (one block per batch) ----------------
__global__ __launch_bounds__(256) void k_push(const float* __restrict__ g_sums,
                                              const float* __restrict__ g_counts,
                                              float* __restrict__ g_cent,   // [B][NSEG][CH]
                                              float* __restrict__ g_push)   // [B]
{
    __shared__ float centB[CH * NSEGC];  // [ch][seg]
    __shared__ float red[4];
    const int b = blockIdx.x;
    const int tid = threadIdx.x;

    for (int i = tid; i < CH * NSEGC; i += 256) {
        const int ch = i >> 6, seg = i & 63;
        const float cnt = fmaxf(g_counts[b * NSEGC + seg], 1.0f);
        const float c = g_sums[(size_t)b * CH * NSEGC + i] / cnt;
        centB[i] = c;
        g_cent[(size_t)b * NSEGC * CH + seg * CH + ch] = c;
    }
    __syncthreads();

    float acc = 0.f;
    for (int t = tid; t < SS * 2016; t += 256) {
        const int s = t / 2016;
        int rem = t % 2016;
        int i = 0;
        while (rem >= 63 - i) { rem -= 63 - i; ++i; }
        const int j = i + 1 + rem;
        float dsum = 0.f;
#pragma unroll
        for (int d = 0; d < DD; ++d) {
            const int ch = s * DD + d;
            dsum += fabsf(centB[ch * NSEGC + i] - centB[ch * NSEGC + j]);
        }
        const float cd = dsum * (1.f / DD);
        const float r = fmaxf(MARGINF - cd, 0.f);
        acc += r * r;
    }
    for (int o = 32; o > 0; o >>= 1) acc += __shfl_down(acc, o, 64);
    if ((tid & 63) == 0) red[tid >> 6] = acc;
    __syncthreads();
    if (tid == 0)
        g_push[b] = (red[0] + red[1] + red[2] + red[3]) * (1.0f / (SS * 2016));
}

// ---------------- kernel C: pull loss from bf16 shadow + last-block finalize ----------------
__global__ __launch_bounds__(256) void k_pull(const unsigned short* __restrict__ t_bf, // [B][CH][P]
                                              const int* __restrict__ labels,
                                              const float* __restrict__ g_cent, // [B][NSEG][CH]
                                              float* __restrict__ g_pull,       // [B]
                                              const float* __restrict__ g_push, // [B]
                                              unsigned* __restrict__ g_done,
                                              float* __restrict__ out)
{
    __shared__ float centL[NSEGC * CSTR];   // [seg][ch]
    __shared__ float red[4];
    const int b    = blockIdx.x / NCHKP;
    const int base = (blockIdx.x % NCHKP) * PXP;
    const int tid  = threadIdx.x;

    for (int i = tid; i < NSEGC * CH; i += 256) {
        const int seg = i >> 5, ch = i & 31;
        centL[seg * CSTR + ch] = g_cent[(size_t)b * NSEGC * CH + i];  // coalesced
    }
    // this thread's 8 pixels: labels loaded directly (32 B/lane, contiguous)
    const int* lp = labels + (size_t)b * PP + base + tid * 8;
    const int4 L0 = ((const int4*)lp)[0];
    const int4 L1 = ((const int4*)lp)[1];
    const int coff[8] = {L0.x * CSTR, L0.y * CSTR, L0.z * CSTR, L0.w * CSTR,
                         L1.x * CSTR, L1.y * CSTR, L1.z * CSTR, L1.w * CSTR};
    __syncthreads();

    float a0[8], a1[8];
#pragma unroll
    for (int j = 0; j < 8; ++j) { a0[j] = 0.f; a1[j] = 0.f; }

    const unsigned short* tb = t_bf + (size_t)b * CH * PP + base + tid * 8;
#pragma unroll
    for (int ch = 0; ch < CH; ++ch) {
        // 64 lanes x 16 B lane-adjacent = 1 KB contiguous per instruction
        const short8 tv = *(const short8*)(tb + (size_t)ch * PP);
#pragma unroll
        for (int j = 0; j < 8; ++j) {
            const float f = __uint_as_float(((unsigned)(unsigned short)tv[j]) << 16);
            const float d = fabsf(f - centL[coff[j] + ch]);
            if (ch < 16) a0[j] += d; else a1[j] += d;
        }
    }

    float total = 0.f;
#pragma unroll
    for (int j = 0; j < 8; ++j) {
        float q;
        q = a0[j] * (1.f / DD); total += q * q;
        q = a1[j] * (1.f / DD); total += q * q;
    }
    for (int o = 32; o > 0; o >>= 1) total += __shfl_down(total, o, 64);
    if ((tid & 63) == 0) red[tid >> 6] = total;
    __syncthreads();

    if (tid == 0) {
        atomicAdd(&g_pull[b], red[0] + red[1] + red[2] + red[3]);
        __threadfence();                               // order my atomics before the counter
        const unsigned prev = atomicAdd(g_done, 1u);
        if (prev == gridDim.x - 1) {                   // last block: all g_pull visible
            float accf = 0.f;
            for (int bb = 0; bb < BB; ++bb) {
                const float pu = atomicAdd(&g_pull[bb], 0.0f);   // coherent read
                const float ph = g_push[bb];                     // written by prior kernel
                accf += ph + 0.1f * (pu * (1.0f / (SS * PP)));
            }
            out[0] = accf * (1.0f / BB);
        }
    }
}

extern "C" void kernel_launch(void* const* d_in, const int* in_sizes, int n_in,
                              void* d_out, int out_size, void* d_ws, size_t ws_size,
                              hipStream_t stream) {
    const float* preds  = (const float*)d_in[0];
    const int*   labels = (const int*)d_in[1];

    float* ws       = (float*)d_ws;
    float* g_sums   = ws;                              // B*CH*NSEG = 8192
    float* g_counts = g_sums + BB * CH * NSEGC;        // B*NSEG    = 256
    float* g_pull   = g_counts + BB * NSEGC;           // B         = 4
    float* g_push   = g_pull + BB;                     // B         = 4
    unsigned* g_done = (unsigned*)(g_push + BB);       // 1
    float* g_cent   = (float*)(g_done + 1);            // B*NSEG*CH = 8192
    unsigned short* t_bf = (unsigned short*)(ws + 16896);  // B*CH*P bf16 = 67 MB, 256B-aligned

    // zero accumulated region (sums, counts, pull, push, done) — replays must not accumulate
    hipMemsetAsync(d_ws, 0,
                   (size_t)(BB * CH * NSEGC + BB * NSEGC + BB + BB + 1) * sizeof(float),
                   stream);

    k_sums<<<BB * NCHUNK, 256, 0, stream>>>(preds, labels, g_sums, g_counts, t_bf);
    k_push<<<BB, 256, 0, stream>>>(g_sums, g_counts, g_cent, g_push);
    k_pull<<<BB * NCHKP, 256, 0, stream>>>(t_bf, labels, g_cent, g_pull, g_push,
                                           g_done, (float*)d_out);
}

// Round 9
// 97.437 us; speedup vs baseline: 1.6034x; 1.0282x over previous
//
#include <hip/hip_runtime.h>
#include <hip/hip_bf16.h>

#define BB 4
#define SS 2
#define DD 16
#define CH 32          // S*D
#define PP (512*512)   // pixels per item
#define NSEGC 64
#define MARGINF 0.25f

// ---- k_sums geometry: 1024 px per block (4 sub-chunks of 256), grid 1024 ----
#define CHUNK 1024
#define NCHUNK (PP/CHUNK)
// ---- k_pull geometry: 2048 px per block (8 px/thread), grid 512 ----
#define PXP 2048
#define NCHKP (PP/PXP)          // 128 per batch
#define CSTR 33                 // centL row stride: bank=(label+ch)%32 -> ~2-way (free)

typedef __attribute__((ext_vector_type(4))) float  f32x4;
typedef __attribute__((ext_vector_type(8))) short  short8;
typedef __attribute__((ext_vector_type(4))) short  short4_t;

__device__ inline short f2bf(float x) {
    union { __hip_bfloat16 h; short s; } u;
    u.h = __float2bfloat16(x);   // RNE
    return u.s;
}

// ---------------- kernel A: segment sums + counts via one-hot MFMA ----------------
// Contiguous staging: each wave-instruction reads 1 KB of one channel row; bf16
// shadow written contiguously; MFMA B-frags via XOR-swizzled LDS tile.
__global__ __launch_bounds__(256, 4) void k_sums(const float* __restrict__ preds,
                                                 const int* __restrict__ labels,
                                                 float* __restrict__ g_sums,    // [B][CH][NSEG]
                                                 float* __restrict__ g_counts,  // [B][NSEG]
                                                 unsigned short* __restrict__ t_bf) // [B][CH][P]
{
    __shared__ float buf[4][CH][68];     // 34816 B; first 16 KB doubles as bf16 tile during MFMA
    __shared__ int   labs[CHUNK];        // 4096 B
    __shared__ float cbuf[4][NSEGC];     // 1024 B
    unsigned short* tile = (unsigned short*)&buf[0][0][0];   // [32 ch][256 px] bf16, swizzled

    const int b    = blockIdx.x / NCHUNK;
    const int base = (blockIdx.x % NCHUNK) * CHUNK;
    const int tid  = threadIdx.x;
    const int w    = tid >> 6;           // wave 0..3
    const int l    = tid & 63;
    const int lm   = l & 15;             // A-row / B-col / D-col
    const int lk   = l >> 4;             // k-group

    ((int4*)labs)[tid] = ((const int4*)(labels + (size_t)b * PP + base))[tid];

    f32x4 acc[4][2];
    f32x4 accc[4];
#pragma unroll
    for (int mt = 0; mt < 4; ++mt) {
        accc[mt] = f32x4{0.f, 0.f, 0.f, 0.f};
#pragma unroll
        for (int nt = 0; nt < 2; ++nt) acc[mt][nt] = f32x4{0.f, 0.f, 0.f, 0.f};
    }
    short8 ones;
#pragma unroll
    for (int j = 0; j < 8; ++j) ones[j] = (short)0x3F80;  // bf16 1.0

    const float*    pb  = preds + (size_t)b * CH * PP + base;
    unsigned short* tbb = t_bf  + (size_t)b * CH * PP + base;

#pragma unroll 1
    for (int sc = 0; sc < 4; ++sc) {
        const int px0 = sc * 256;
        // ---- stage: wave w loads channels w*8..w*8+7, 1 KB contiguous per instr ----
#pragma unroll
        for (int i = 0; i < 8; ++i) {
            const int ch = w * 8 + i;
            const float4 v = ((const float4*)(pb + (size_t)ch * PP + px0))[l];
            short4_t s4;
            s4[0] = f2bf(v.x); s4[1] = f2bf(v.y); s4[2] = f2bf(v.z); s4[3] = f2bf(v.w);
            // contiguous shadow store: 64 lanes x 8 B = 512 B per instruction
            *(short4_t*)(tbb + (size_t)ch * PP + px0 + 4 * l) = s4;
            // swizzled LDS tile write (granule g=l>>1, XOR ch&7) — conflict-free
            const int g = (l >> 1) ^ (ch & 7);
            *(short4_t*)&tile[ch * 256 + g * 8 + (l & 1) * 4] = s4;
        }
        __syncthreads();   // tile + labs visible

        // ---- MFMA: wave w owns K-chunks c = 2w, 2w+1 of this sub-chunk ----
#pragma unroll
        for (int cc = 0; cc < 2; ++cc) {
            const int c  = 2 * w + cc;
            const int kb = px0 + c * 32 + lk * 8;      // this lane's 8 pixels
            const int4 L0 = *(const int4*)&labs[kb];
            const int4 L1 = *(const int4*)&labs[kb + 4];
            const int labv[8] = {L0.x, L0.y, L0.z, L0.w, L1.x, L1.y, L1.z, L1.w};

            short8 af[4];
#pragma unroll
            for (int mt = 0; mt < 4; ++mt) {
                const int target = mt * 16 + lm;
#pragma unroll
                for (int j = 0; j < 8; ++j)
                    af[mt][j] = (labv[j] == target) ? (short)0x3F80 : (short)0;
            }

#pragma unroll
            for (int nt = 0; nt < 2; ++nt) {
                const int ch = nt * 16 + lm;
                const int g  = (c * 4 + lk) ^ (ch & 7);    // matches write swizzle
                const short8 bf = *(const short8*)&tile[ch * 256 + g * 8];
#pragma unroll
                for (int mt = 0; mt < 4; ++mt)
                    acc[mt][nt] = __builtin_amdgcn_mfma_f32_16x16x32_bf16(af[mt], bf, acc[mt][nt], 0, 0, 0);
            }
#pragma unroll
            for (int mt = 0; mt < 4; ++mt)
                accc[mt] = __builtin_amdgcn_mfma_f32_16x16x32_bf16(af[mt], ones, accc[mt], 0, 0, 0);
        }
        __syncthreads();   // all reads of tile done before next staging / buf write
    }

    // D layout: col = lane&15, row = (lane>>4)*4 + reg  (m89-verified)
#pragma unroll
    for (int mt = 0; mt < 4; ++mt) {
#pragma unroll
        for (int nt = 0; nt < 2; ++nt)
            *(f32x4*)&buf[w][nt * 16 + lm][mt * 16 + lk * 4] = acc[mt][nt];
        if (lm == 0)
            *(f32x4*)&cbuf[w][mt * 16 + lk * 4] = accc[mt];
    }
    __syncthreads();

    for (int i = tid; i < CH * NSEGC; i += 256) {
        const int col = i >> 6, row = i & 63;   // i = ch*64 + seg
        const float s = buf[0][col][row] + buf[1][col][row] + buf[2][col][row] + buf[3][col][row];
        atomicAdd(&g_sums[(size_t)b * CH * NSEGC + i], s);
    }
    if (tid < NSEGC)
        atomicAdd(&g_counts[b * NSEGC + tid],
                  cbuf[0][tid] + cbuf[1][tid] + cbuf[2][tid] + cbuf[3][tid]);
}

// ---------------- kernel B: centroids + push loss (one block per batch) ----------------
__global__ __launch_bounds__(256) void k_push(const float* __restrict__ g_sums,
                                              const float* __restrict__ g_counts,
                                              float* __restrict__ g_cent,   // [B][NSEG][CH]
                                              float* __restrict__ g_push)   // [B]
{
    __shared__ float centB[CH * NSEGC];  // [ch][seg]
    __shared__ float red[4];
    const int b = blockIdx.x;
    const int tid = threadIdx.x;

    for (int i = tid; i < CH * NSEGC; i += 256) {
        const int ch = i >> 6, seg = i & 63;
        const float cnt = fmaxf(g_counts[b * NSEGC + seg], 1.0f);
        const float c = g_sums[(size_t)b * CH * NSEGC + i] / cnt;
        centB[i] = c;
        g_cent[(size_t)b * NSEGC * CH + seg * CH + ch] = c;
    }
    __syncthreads();

    float acc = 0.f;
    for (int t = tid; t < SS * 2016; t += 256) {
        const int s = t / 2016;
        int rem = t % 2016;
        int i = 0;
        while (rem >= 63 - i) { rem -= 63 - i; ++i; }
        const int j = i + 1 + rem;
        float dsum = 0.f;
#pragma unroll
        for (int d = 0; d < DD; ++d) {
            const int ch = s * DD + d;
            dsum += fabsf(centB[ch * NSEGC + i] - centB[ch * NSEGC + j]);
        }
        const float cd = dsum * (1.f / DD);
        const float r = fmaxf(MARGINF - cd, 0.f);
        acc += r * r;
    }
    for (int o = 32; o > 0; o >>= 1) acc += __shfl_down(acc, o, 64);
    if ((tid & 63) == 0) red[tid >> 6] = acc;
    __syncthreads();
    if (tid == 0)
        g_push[b] = (red[0] + red[1] + red[2] + red[3]) * (1.0f / (SS * 2016));
}

// ---------------- kernel C: pull loss from bf16 shadow + last-block finalize ----------------
__global__ __launch_bounds__(256) void k_pull(const unsigned short* __restrict__ t_bf, // [B][CH][P]
                                              const int* __restrict__ labels,
                                              const float* __restrict__ g_cent, // [B][NSEG][CH]
                                              float* __restrict__ g_pull,       // [B]
                                              const float* __restrict__ g_push, // [B]
                                              unsigned* __restrict__ g_done,
                                              float* __restrict__ out)
{
    __shared__ float centL[NSEGC * CSTR];   // [seg][ch]
    __shared__ float red[4];
    const int b    = blockIdx.x / NCHKP;
    const int base = (blockIdx.x % NCHKP) * PXP;
    const int tid  = threadIdx.x;

    for (int i = tid; i < NSEGC * CH; i += 256) {
        const int seg = i >> 5, ch = i & 31;
        centL[seg * CSTR + ch] = g_cent[(size_t)b * NSEGC * CH + i];  // coalesced
    }
    // this thread's 8 pixels: labels loaded directly (32 B/lane, contiguous)
    const int* lp = labels + (size_t)b * PP + base + tid * 8;
    const int4 L0 = ((const int4*)lp)[0];
    const int4 L1 = ((const int4*)lp)[1];
    const int coff[8] = {L0.x * CSTR, L0.y * CSTR, L0.z * CSTR, L0.w * CSTR,
                         L1.x * CSTR, L1.y * CSTR, L1.z * CSTR, L1.w * CSTR};
    __syncthreads();

    float a0[8], a1[8];
#pragma unroll
    for (int j = 0; j < 8; ++j) { a0[j] = 0.f; a1[j] = 0.f; }

    const unsigned short* tb = t_bf + (size_t)b * CH * PP + base + tid * 8;
#pragma unroll
    for (int ch = 0; ch < CH; ++ch) {
        // 64 lanes x 16 B lane-adjacent = 1 KB contiguous per instruction
        const short8 tv = *(const short8*)(tb + (size_t)ch * PP);
#pragma unroll
        for (int j = 0; j < 8; ++j) {
            const float f = __uint_as_float(((unsigned)(unsigned short)tv[j]) << 16);
            const float d = fabsf(f - centL[coff[j] + ch]);
            if (ch < 16) a0[j] += d; else a1[j] += d;
        }
    }

    float total = 0.f;
#pragma unroll
    for (int j = 0; j < 8; ++j) {
        float q;
        q = a0[j] * (1.f / DD); total += q * q;
        q = a1[j] * (1.f / DD); total += q * q;
    }
    for (int o = 32; o > 0; o >>= 1) total += __shfl_down(total, o, 64);
    if ((tid & 63) == 0) red[tid >> 6] = total;
    __syncthreads();

    if (tid == 0) {
        atomicAdd(&g_pull[b], red[0] + red[1] + red[2] + red[3]);
        __threadfence();                               // order my atomics before the counter
        const unsigned prev = atomicAdd(g_done, 1u);
        if (prev == gridDim.x - 1) {                   // last block: all g_pull visible
            float accf = 0.f;
            for (int bb = 0; bb < BB; ++bb) {
                const float pu = atomicAdd(&g_pull[bb], 0.0f);   // coherent read
                const float ph = g_push[bb];                     // written by prior kernel
                accf += ph + 0.1f * (pu * (1.0f / (SS * PP)));
            }
            out[0] = accf * (1.0f / BB);
        }
    }
}

extern "C" void kernel_launch(void* const* d_in, const int* in_sizes, int n_in,
                              void* d_out, int out_size, void* d_ws, size_t ws_size,
                              hipStream_t stream) {
    const float* preds  = (const float*)d_in[0];
    const int*   labels = (const int*)d_in[1];

    float* ws       = (float*)d_ws;
    float* g_sums   = ws;                              // B*CH*NSEG = 8192
    float* g_counts = g_sums + BB * CH * NSEGC;        // B*NSEG    = 256
    float* g_pull   = g_counts + BB * NSEGC;           // B         = 4
    float* g_push   = g_pull + BB;                     // B         = 4
    unsigned* g_done = (unsigned*)(g_push + BB);       // 1
    float* g_cent   = (float*)(g_done + 1);            // B*NSEG*CH = 8192
    unsigned short* t_bf = (unsigned short*)(ws + 16896);  // B*CH*P bf16 = 67 MB

    // zero accumulated region (sums, counts, pull, push, done) — replays must not accumulate
    hipMemsetAsync(d_ws, 0,
                   (size_t)(BB * CH * NSEGC + BB * NSEGC + BB + BB + 1) * sizeof(float),
                   stream);

    k_sums<<<BB * NCHUNK, 256, 0, stream>>>(preds, labels, g_sums, g_counts, t_bf);
    k_push<<<BB, 256, 0, stream>>>(g_sums, g_counts, g_cent, g_push);
    k_pull<<<BB * NCHKP, 256, 0, stream>>>(t_bf, labels, g_cent, g_pull, g_push,
                                           g_done, (float*)d_out);
}